// Round 3
// baseline (487.328 us; speedup 1.0000x reference)
//
#include <hip/hip_runtime.h>
#include <cstdint>
#include <cstddef>

// ---------------- problem constants ----------------
#define E_EDGES     524288
#define N_TOT       16384      // total nodes (8 graphs x 2048)
#define HID         64
#define B_GR        8
#define KTOT        131072     // NPG*HID, FC1 inner dim
#define NJ          2048       // FC1 output width
#define MAXN        15

// FC1 tiling
#define KC          256        // k-chunk
#define NCHUNK      512        // KTOT/KC
#define JT          4          // j-tiles of 512 (256 threads x float2)

// ---------------- workspace layout (bytes) ----------------
#define OFF_DEGI    0x0u         // 64 KB (16384 int)
#define OFF_DIS     0x10000u     // 64 KB
#define OFF_AGGX    0x20000u     // 256 KB (16384 x 4 f32)
#define OFF_ROWPTR  0x60000u     // 64 KB + 4 (pad to 128K)
#define OFF_CURSOR  0x80000u     // 64 KB
#define OFF_CSR     0x90000u     // 4 MB (524288 int2)
#define OFF_H1      0x490000u    // 4 MB
#define OFF_AGG2    0x890000u    // 4 MB
#define OFF_H2      0xC90000u    // 4 MB
#define OFF_Z       0x1090000u   // 64 KB
#define OFF_TMP     0x10A0000u   // 512 KB (8 x 16384 f32)
#define OFF_PART    0x1200000u   // 33.55 MB (512 x 8 x 2048 f32)

__device__ __forceinline__ float selu_f(float x) {
    const float scale = 1.0507009873554805f;
    const float alpha = 1.6732632423543772f;
    return x > 0.0f ? scale * x : scale * alpha * expm1f(x);
}

// ---- degree (in-degree over dst; +1 self-loop handled in dis) ----
__global__ void deg_kernel(const int* __restrict__ dst, int* __restrict__ degi) {
    int e = blockIdx.x * 256 + threadIdx.x;
    if (e < E_EDGES) atomicAdd(&degi[dst[e]], 1);
}

// ---- exclusive scan of degi -> rowptr, plus dis = rsqrt(deg+1) (1 block) ----
__global__ void scan_kernel(const int* __restrict__ degi, int* __restrict__ rowptr,
                            float* __restrict__ dis) {
    __shared__ int pref[257];
    __shared__ int sums[256];
    int t = threadIdx.x;
    int base = t * 64;
    int s = 0;
    for (int i = 0; i < 64; ++i) s += degi[base + i];
    sums[t] = s;
    __syncthreads();
    if (t == 0) {
        int run = 0;
        for (int i = 0; i < 256; ++i) { pref[i] = run; run += sums[i]; }
        pref[256] = run;
    }
    __syncthreads();
    int run = pref[t];
    for (int i = 0; i < 64; ++i) {
        int dg = degi[base + i];
        rowptr[base + i] = run; run += dg;
        dis[base + i] = rsqrtf((float)(dg + 1));
    }
    if (t == 255) rowptr[N_TOT] = pref[256];
}

// ---- fused: CSR scatter (col + weight) AND layer-1 aggregation atomics ----
__global__ void scatter_agg1_kernel(const int* __restrict__ src, const int* __restrict__ dst,
                                    const float* __restrict__ x, const float* __restrict__ dis,
                                    const int* __restrict__ rowptr, int* __restrict__ cursor,
                                    int2* __restrict__ csr, float* __restrict__ aggx) {
    int e = blockIdx.x * 256 + threadIdx.x;
    if (e >= E_EDGES) return;
    int s = src[e], d = dst[e];
    float dss = dis[s];
    float nrm = dss * dis[d];
    int pos = atomicAdd(&cursor[d], 1);
    int2 cw; cw.x = s; cw.y = __float_as_int(dss);
    csr[rowptr[d] + pos] = cw;
    const float4 xv = *reinterpret_cast<const float4*>(x + (size_t)s * 4);
    float* o = aggx + (size_t)d * 4;
    atomicAdd(o + 0, xv.x * nrm);
    atomicAdd(o + 1, xv.y * nrm);
    atomicAdd(o + 2, xv.z * nrm);
    atomicAdd(o + 3, xv.w * nrm);
}

// ---- h1 = selu( (aggx + x*dis^2) @ W1 + b1 ), thread per (node, oc) ----
__global__ void h1_kernel(const float* __restrict__ aggx, const float* __restrict__ x,
                          const float* __restrict__ dis, const float* __restrict__ W1,
                          const float* __restrict__ b1, float* __restrict__ h1) {
    int t = blockIdx.x * 256 + threadIdx.x;     // N_TOT*64 threads
    int i = t >> 6, oc = t & 63;
    float ds = dis[i];
    float d2 = ds * ds;
    const float4 a  = *reinterpret_cast<const float4*>(aggx + (size_t)i * 4);
    const float4 xv = *reinterpret_cast<const float4*>(x    + (size_t)i * 4);
    float v = b1[oc];
    v = fmaf(a.x + xv.x * d2, W1[       oc], v);
    v = fmaf(a.y + xv.y * d2, W1[ 64 +  oc], v);
    v = fmaf(a.z + xv.z * d2, W1[128 +  oc], v);
    v = fmaf(a.w + xv.w * d2, W1[192 +  oc], v);
    h1[t] = selu_f(v);
}

// ---- layer-2 aggregation via CSR gather (csr packs src + dis[src]) ----
__launch_bounds__(256)
__global__ void agg2_gather_kernel(const int* __restrict__ rowptr, const int2* __restrict__ csr,
                                   const float* __restrict__ h1, const float* __restrict__ dis,
                                   float* __restrict__ agg2) {
    int node = blockIdx.x * 4 + (threadIdx.x >> 6);
    int c = threadIdx.x & 63;
    int beg = rowptr[node], end = rowptr[node + 1];
    float acc = 0.f;
    int i = beg;
    for (; i + 1 < end; i += 2) {
        int2 a = csr[i];
        int2 b = csr[i + 1];
        acc = fmaf(h1[(size_t)a.x * HID + c], __int_as_float(a.y), acc);
        acc = fmaf(h1[(size_t)b.x * HID + c], __int_as_float(b.y), acc);
    }
    if (i < end) {
        int2 a = csr[i];
        acc = fmaf(h1[(size_t)a.x * HID + c], __int_as_float(a.y), acc);
    }
    agg2[(size_t)node * HID + c] = acc * dis[node];
}

// ---- h2 = selu( (agg2 + h1*dis^2) @ W2 + b2 ), W2 staged in LDS ----
__launch_bounds__(256)
__global__ void h2_kernel(const float* __restrict__ agg2v, const float* __restrict__ h1,
                          const float* __restrict__ dis, const float* __restrict__ W2,
                          const float* __restrict__ b2, float* __restrict__ h2) {
    __shared__ float w2s[HID * HID];      // 16 KB
    __shared__ float in2s[4 * HID];
    for (int idx = threadIdx.x; idx < HID * HID; idx += 256) w2s[idx] = W2[idx];
    int node = blockIdx.x * 4 + (threadIdx.x >> 6);
    int oc = threadIdx.x & 63;
    float ds = dis[node];
    in2s[threadIdx.x] = agg2v[(size_t)node * HID + oc] + h1[(size_t)node * HID + oc] * ds * ds;
    __syncthreads();
    const float* inrow = &in2s[(threadIdx.x >> 6) * HID];
    float acc = b2[oc];
    #pragma unroll
    for (int c = 0; c < HID; ++c) acc = fmaf(inrow[c], w2s[c * HID + oc], acc);
    h2[(size_t)node * HID + oc] = selu_f(acc);
}

// ---- FC1: partials[chunk][b][j] = sum_{k in chunk} h2[b][k] * Wf1[k][j] ----
// grid (JT=4, NCHUNK=512), 256 threads, float2 per thread; 32 waves/CU target
__launch_bounds__(256, 8)
__global__ void fc1_kernel(const float* __restrict__ h2, const float* __restrict__ Wf1,
                           float* __restrict__ partials) {
    __shared__ float hch[B_GR][KC];       // 8 KB
    const int jt = blockIdx.x;            // 0..3
    const int chunk = blockIdx.y;         // 0..511
    const int k0 = chunk * KC;
    for (int idx = threadIdx.x; idx < B_GR * KC; idx += 256) {
        int b = idx >> 8;                 // KC = 256
        int kk = idx & (KC - 1);
        hch[b][kk] = h2[(size_t)b * KTOT + k0 + kk];
    }
    __syncthreads();
    float2 acc[B_GR];
    #pragma unroll
    for (int b = 0; b < B_GR; ++b) acc[b] = make_float2(0.f, 0.f);
    const int j = jt * 512 + threadIdx.x * 2;
    const float* wp = Wf1 + (size_t)k0 * NJ + j;
    #pragma unroll 8
    for (int kk = 0; kk < KC; ++kk) {
        float2 w = *reinterpret_cast<const float2*>(wp);
        wp += NJ;
        #pragma unroll
        for (int b = 0; b < B_GR; ++b) {
            float hv = hch[b][kk];
            acc[b].x = fmaf(w.x, hv, acc[b].x);
            acc[b].y = fmaf(w.y, hv, acc[b].y);
        }
    }
    float* pp = partials + (size_t)chunk * (B_GR * NJ) + j;
    #pragma unroll
    for (int b = 0; b < B_GR; ++b)
        *reinterpret_cast<float2*>(pp + (size_t)b * NJ) = acc[b];
}

// ---- two-stage reduce over chunks ----
__global__ void fc1_reduce1_kernel(const float* __restrict__ partials, float* __restrict__ tmp) {
    int idx = blockIdx.x * 256 + threadIdx.x;   // 0..16383
    int g = blockIdx.y;                         // 0..7  (64 chunks each)
    float s = 0.f;
    const float* p = partials + (size_t)(g * 64) * (B_GR * NJ) + idx;
    #pragma unroll 8
    for (int c = 0; c < 64; ++c) { s += *p; p += B_GR * NJ; }
    tmp[(size_t)g * (B_GR * NJ) + idx] = s;
}

__global__ void fc1_reduce2_kernel(const float* __restrict__ tmp,
                                   const float* __restrict__ bf1, float* __restrict__ z) {
    int idx = blockIdx.x * 256 + threadIdx.x;   // 16384
    float s = 0.f;
    #pragma unroll
    for (int g = 0; g < 8; ++g) s += tmp[(size_t)g * (B_GR * NJ) + idx];
    int j = idx & (NJ - 1);
    z[idx] = selu_f(s + bf1[j]);
}

// ---- FC2: out[b][m] = z[b,:] . Wf2[:,m] + bf2[m]; 1 block per b ----
__global__ void fc2_kernel(const float* __restrict__ z, const float* __restrict__ Wf2,
                           const float* __restrict__ bf2, float* __restrict__ out) {
    int b = blockIdx.x;
    int t = threadIdx.x;  // 64
    float acc[MAXN];
    #pragma unroll
    for (int m = 0; m < MAXN; ++m) acc[m] = 0.f;
    for (int j = t; j < NJ; j += 64) {
        float zv = z[(size_t)b * NJ + j];
        const float* wr = Wf2 + (size_t)j * MAXN;
        #pragma unroll
        for (int m = 0; m < MAXN; ++m) acc[m] = fmaf(zv, wr[m], acc[m]);
    }
    #pragma unroll
    for (int m = 0; m < MAXN; ++m) {
        float v = acc[m];
        for (int off = 32; off > 0; off >>= 1) v += __shfl_down(v, off, 64);
        if (t == 0) out[b * MAXN + m] = v + bf2[m];
    }
}

extern "C" void kernel_launch(void* const* d_in, const int* in_sizes, int n_in,
                              void* d_out, int out_size, void* d_ws, size_t ws_size,
                              hipStream_t stream) {
    const float* x    = (const float*)d_in[0];
    const int*   ei   = (const int*)d_in[1];      // int32 (JAX x64 disabled)
    const float* W1   = (const float*)d_in[2];
    const float* b1   = (const float*)d_in[3];
    const float* W2   = (const float*)d_in[4];
    const float* b2   = (const float*)d_in[5];
    const float* Wf1  = (const float*)d_in[6];
    const float* bf1  = (const float*)d_in[7];
    const float* Wf2  = (const float*)d_in[8];
    const float* bf2  = (const float*)d_in[9];
    float* out = (float*)d_out;

    const int* src = ei;
    const int* dst = ei + E_EDGES;

    char* ws = (char*)d_ws;
    int*   degi   = (int*)  (ws + OFF_DEGI);
    float* dis    = (float*)(ws + OFF_DIS);
    float* aggx   = (float*)(ws + OFF_AGGX);
    int*   rowptr = (int*)  (ws + OFF_ROWPTR);
    int*   cursor = (int*)  (ws + OFF_CURSOR);
    int2*  csr    = (int2*) (ws + OFF_CSR);
    float* h1     = (float*)(ws + OFF_H1);
    float* agg2   = (float*)(ws + OFF_AGG2);
    float* h2     = (float*)(ws + OFF_H2);
    float* z      = (float*)(ws + OFF_Z);
    float* tmp    = (float*)(ws + OFF_TMP);
    float* parts  = (float*)(ws + OFF_PART);

    // zero the accumulated buffers (graph-capture-safe)
    hipMemsetAsync(degi,   0, N_TOT * sizeof(int), stream);
    hipMemsetAsync(cursor, 0, N_TOT * sizeof(int), stream);
    hipMemsetAsync(aggx,   0, (size_t)N_TOT * 4 * sizeof(float), stream);

    deg_kernel <<<E_EDGES / 256, 256, 0, stream>>>(dst, degi);
    scan_kernel<<<1, 256, 0, stream>>>(degi, rowptr, dis);
    scatter_agg1_kernel<<<E_EDGES / 256, 256, 0, stream>>>(src, dst, x, dis, rowptr,
                                                           cursor, csr, aggx);
    h1_kernel  <<<(N_TOT * HID) / 256, 256, 0, stream>>>(aggx, x, dis, W1, b1, h1);
    agg2_gather_kernel<<<N_TOT / 4, 256, 0, stream>>>(rowptr, csr, h1, dis, agg2);
    h2_kernel  <<<N_TOT / 4, 256, 0, stream>>>(agg2, h1, dis, W2, b2, h2);
    fc1_kernel <<<dim3(JT, NCHUNK), 256, 0, stream>>>(h2, Wf1, parts);
    fc1_reduce1_kernel<<<dim3(64, 8), 256, 0, stream>>>(parts, tmp);
    fc1_reduce2_kernel<<<64, 256, 0, stream>>>(tmp, bf1, z);
    fc2_kernel <<<B_GR, 64, 0, stream>>>(z, Wf2, bf2, out);
}

// Round 4
// 436.533 us; speedup vs baseline: 1.1164x; 1.1164x over previous
//
#include <hip/hip_runtime.h>
#include <cstdint>
#include <cstddef>

// ---------------- problem constants ----------------
#define E_EDGES     524288
#define N_TOT       16384      // total nodes (8 graphs x 2048)
#define HID         64
#define B_GR        8
#define KTOT        131072     // NPG*HID, FC1 inner dim
#define NJ          2048       // FC1 output width
#define MAXN        15

// FC1 tiling: one block = full 2048-wide row (512 thr x float4), KC rows
#define KC          256
#define NCHUNK      512        // KTOT/KC

// ---------------- workspace layout (bytes) ----------------
// [0, 0x60000) is zeroed with ONE memset: degi | cursor | aggx
#define OFF_DEGI    0x0u         // 64 KB (16384 int)
#define OFF_CURSOR  0x10000u     // 64 KB
#define OFF_AGGX    0x20000u     // 256 KB (16384 x 4 f32)
#define OFF_DIS     0x60000u     // 64 KB
#define OFF_ROWPTR  0x70000u     // 64 KB + 4 (padded to 128 KB)
#define OFF_CSR     0x90000u     // 4 MB (524288 int2)
#define OFF_H1      0x490000u    // 4 MB
#define OFF_AGG2    0x890000u    // 4 MB
#define OFF_H2      0xC90000u    // 4 MB
#define OFF_Z       0x1090000u   // 64 KB
#define OFF_TMP     0x10A0000u   // 512 KB (8 x 16384 f32)
#define OFF_PART    0x1200000u   // 33.55 MB (512 x 8 x 2048 f32)

__device__ __forceinline__ float selu_f(float x) {
    const float scale = 1.0507009873554805f;
    const float alpha = 1.6732632423543772f;
    return x > 0.0f ? scale * x : scale * alpha * expm1f(x);
}

// ---- degree (in-degree over dst; +1 self-loop handled in dis) ----
__global__ void deg_kernel(const int* __restrict__ dst, int* __restrict__ degi) {
    int e = blockIdx.x * 256 + threadIdx.x;
    if (e < E_EDGES) atomicAdd(&degi[dst[e]], 1);
}

// ---- exclusive scan of degi -> rowptr, plus dis = rsqrt(deg+1) (1 block) ----
__global__ void scan_kernel(const int* __restrict__ degi, int* __restrict__ rowptr,
                            float* __restrict__ dis) {
    __shared__ int pref[257];
    __shared__ int sums[256];
    int t = threadIdx.x;
    int base = t * 64;
    int s = 0;
    for (int i = 0; i < 64; ++i) s += degi[base + i];
    sums[t] = s;
    __syncthreads();
    if (t == 0) {
        int run = 0;
        for (int i = 0; i < 256; ++i) { pref[i] = run; run += sums[i]; }
        pref[256] = run;
    }
    __syncthreads();
    int run = pref[t];
    for (int i = 0; i < 64; ++i) {
        int dg = degi[base + i];
        rowptr[base + i] = run; run += dg;
        dis[base + i] = rsqrtf((float)(dg + 1));
    }
    if (t == 255) rowptr[N_TOT] = pref[256];
}

// ---- fused: CSR scatter (col + weight) AND layer-1 aggregation atomics ----
__global__ void scatter_agg1_kernel(const int* __restrict__ src, const int* __restrict__ dst,
                                    const float* __restrict__ x, const float* __restrict__ dis,
                                    const int* __restrict__ rowptr, int* __restrict__ cursor,
                                    int2* __restrict__ csr, float* __restrict__ aggx) {
    int e = blockIdx.x * 256 + threadIdx.x;
    if (e >= E_EDGES) return;
    int s = src[e], d = dst[e];
    float dss = dis[s];
    float nrm = dss * dis[d];
    int pos = atomicAdd(&cursor[d], 1);
    int2 cw; cw.x = s; cw.y = __float_as_int(dss);
    csr[rowptr[d] + pos] = cw;
    const float4 xv = *reinterpret_cast<const float4*>(x + (size_t)s * 4);
    float* o = aggx + (size_t)d * 4;
    atomicAdd(o + 0, xv.x * nrm);
    atomicAdd(o + 1, xv.y * nrm);
    atomicAdd(o + 2, xv.z * nrm);
    atomicAdd(o + 3, xv.w * nrm);
}

// ---- h1 = selu( (aggx + x*dis^2) @ W1 + b1 ), thread per (node, oc) ----
__global__ void h1_kernel(const float* __restrict__ aggx, const float* __restrict__ x,
                          const float* __restrict__ dis, const float* __restrict__ W1,
                          const float* __restrict__ b1, float* __restrict__ h1) {
    int t = blockIdx.x * 256 + threadIdx.x;     // N_TOT*64 threads
    int i = t >> 6, oc = t & 63;
    float ds = dis[i];
    float d2 = ds * ds;
    const float4 a  = *reinterpret_cast<const float4*>(aggx + (size_t)i * 4);
    const float4 xv = *reinterpret_cast<const float4*>(x    + (size_t)i * 4);
    float v = b1[oc];
    v = fmaf(a.x + xv.x * d2, W1[       oc], v);
    v = fmaf(a.y + xv.y * d2, W1[ 64 +  oc], v);
    v = fmaf(a.z + xv.z * d2, W1[128 +  oc], v);
    v = fmaf(a.w + xv.w * d2, W1[192 +  oc], v);
    h1[t] = selu_f(v);
}

// ---- layer-2 aggregation via CSR gather (csr packs src + dis[src]) ----
__launch_bounds__(256)
__global__ void agg2_gather_kernel(const int* __restrict__ rowptr, const int2* __restrict__ csr,
                                   const float* __restrict__ h1, const float* __restrict__ dis,
                                   float* __restrict__ agg2) {
    int node = blockIdx.x * 4 + (threadIdx.x >> 6);
    int c = threadIdx.x & 63;
    int beg = rowptr[node], end = rowptr[node + 1];
    float acc = 0.f;
    int i = beg;
    for (; i + 3 < end; i += 4) {
        int2 a = csr[i];
        int2 b = csr[i + 1];
        int2 cc = csr[i + 2];
        int2 dd = csr[i + 3];
        acc = fmaf(h1[(size_t)a.x  * HID + c], __int_as_float(a.y),  acc);
        acc = fmaf(h1[(size_t)b.x  * HID + c], __int_as_float(b.y),  acc);
        acc = fmaf(h1[(size_t)cc.x * HID + c], __int_as_float(cc.y), acc);
        acc = fmaf(h1[(size_t)dd.x * HID + c], __int_as_float(dd.y), acc);
    }
    for (; i < end; ++i) {
        int2 a = csr[i];
        acc = fmaf(h1[(size_t)a.x * HID + c], __int_as_float(a.y), acc);
    }
    agg2[(size_t)node * HID + c] = acc * dis[node];
}

// ---- h2 = selu( (agg2 + h1*dis^2) @ W2 + b2 ), W2 staged in LDS ----
__launch_bounds__(256)
__global__ void h2_kernel(const float* __restrict__ agg2v, const float* __restrict__ h1,
                          const float* __restrict__ dis, const float* __restrict__ W2,
                          const float* __restrict__ b2, float* __restrict__ h2) {
    __shared__ float w2s[HID * HID];      // 16 KB
    __shared__ float in2s[4 * HID];
    for (int idx = threadIdx.x; idx < HID * HID; idx += 256) w2s[idx] = W2[idx];
    int node = blockIdx.x * 4 + (threadIdx.x >> 6);
    int oc = threadIdx.x & 63;
    float ds = dis[node];
    in2s[threadIdx.x] = agg2v[(size_t)node * HID + oc] + h1[(size_t)node * HID + oc] * ds * ds;
    __syncthreads();
    const float* inrow = &in2s[(threadIdx.x >> 6) * HID];
    float acc = b2[oc];
    #pragma unroll
    for (int c = 0; c < HID; ++c) acc = fmaf(inrow[c], w2s[c * HID + oc], acc);
    h2[(size_t)node * HID + oc] = selu_f(acc);
}

// ---- FC1: block = 512 thr x float4 = full 2048-wide row; KC contiguous rows.
// Each block streams a contiguous 2 MB slab of Wf1 exactly once.
__launch_bounds__(512, 4)
__global__ void fc1_kernel(const float* __restrict__ h2, const float* __restrict__ Wf1,
                           float* __restrict__ partials) {
    __shared__ float hch[B_GR * KC];      // 8 KB, [b][kk]
    const int chunk = blockIdx.x;         // 0..NCHUNK-1
    const int k0 = chunk * KC;
    for (int idx = threadIdx.x; idx < B_GR * KC; idx += 512) {
        int b = idx >> 8;                 // KC = 256
        int kk = idx & (KC - 1);
        hch[idx] = h2[(size_t)b * KTOT + k0 + kk];
    }
    __syncthreads();
    float4 acc[B_GR];
    #pragma unroll
    for (int b = 0; b < B_GR; ++b) acc[b] = make_float4(0.f, 0.f, 0.f, 0.f);
    const int j = threadIdx.x * 4;
    const float* wp = Wf1 + (size_t)k0 * NJ + j;
    #pragma unroll 4
    for (int kk = 0; kk < KC; ++kk) {
        float4 w = *reinterpret_cast<const float4*>(wp);
        wp += NJ;
        #pragma unroll
        for (int b = 0; b < B_GR; ++b) {
            float hv = hch[b * KC + kk];
            acc[b].x = fmaf(w.x, hv, acc[b].x);
            acc[b].y = fmaf(w.y, hv, acc[b].y);
            acc[b].z = fmaf(w.z, hv, acc[b].z);
            acc[b].w = fmaf(w.w, hv, acc[b].w);
        }
    }
    float* pp = partials + (size_t)chunk * (B_GR * NJ) + j;
    #pragma unroll
    for (int b = 0; b < B_GR; ++b)
        *reinterpret_cast<float4*>(pp + (size_t)b * NJ) = acc[b];
}

// ---- two-stage reduce over chunks ----
__global__ void fc1_reduce1_kernel(const float* __restrict__ partials, float* __restrict__ tmp) {
    int idx = blockIdx.x * 256 + threadIdx.x;   // 0..16383
    int g = blockIdx.y;                         // 0..7  (64 chunks each)
    float s = 0.f;
    const float* p = partials + (size_t)(g * 64) * (B_GR * NJ) + idx;
    #pragma unroll 8
    for (int c = 0; c < 64; ++c) { s += *p; p += B_GR * NJ; }
    tmp[(size_t)g * (B_GR * NJ) + idx] = s;
}

__global__ void fc1_reduce2_kernel(const float* __restrict__ tmp,
                                   const float* __restrict__ bf1, float* __restrict__ z) {
    int idx = blockIdx.x * 256 + threadIdx.x;   // 16384
    float s = 0.f;
    #pragma unroll
    for (int g = 0; g < 8; ++g) s += tmp[(size_t)g * (B_GR * NJ) + idx];
    int j = idx & (NJ - 1);
    z[idx] = selu_f(s + bf1[j]);
}

// ---- FC2: out[b][m] = z[b,:] . Wf2[:,m] + bf2[m]; 1 block per b ----
__global__ void fc2_kernel(const float* __restrict__ z, const float* __restrict__ Wf2,
                           const float* __restrict__ bf2, float* __restrict__ out) {
    int b = blockIdx.x;
    int t = threadIdx.x;  // 64
    float acc[MAXN];
    #pragma unroll
    for (int m = 0; m < MAXN; ++m) acc[m] = 0.f;
    for (int j = t; j < NJ; j += 64) {
        float zv = z[(size_t)b * NJ + j];
        const float* wr = Wf2 + (size_t)j * MAXN;
        #pragma unroll
        for (int m = 0; m < MAXN; ++m) acc[m] = fmaf(zv, wr[m], acc[m]);
    }
    #pragma unroll
    for (int m = 0; m < MAXN; ++m) {
        float v = acc[m];
        for (int off = 32; off > 0; off >>= 1) v += __shfl_down(v, off, 64);
        if (t == 0) out[b * MAXN + m] = v + bf2[m];
    }
}

extern "C" void kernel_launch(void* const* d_in, const int* in_sizes, int n_in,
                              void* d_out, int out_size, void* d_ws, size_t ws_size,
                              hipStream_t stream) {
    const float* x    = (const float*)d_in[0];
    const int*   ei   = (const int*)d_in[1];      // int32 (JAX x64 disabled)
    const float* W1   = (const float*)d_in[2];
    const float* b1   = (const float*)d_in[3];
    const float* W2   = (const float*)d_in[4];
    const float* b2   = (const float*)d_in[5];
    const float* Wf1  = (const float*)d_in[6];
    const float* bf1  = (const float*)d_in[7];
    const float* Wf2  = (const float*)d_in[8];
    const float* bf2  = (const float*)d_in[9];
    float* out = (float*)d_out;

    const int* src = ei;
    const int* dst = ei + E_EDGES;

    char* ws = (char*)d_ws;
    int*   degi   = (int*)  (ws + OFF_DEGI);
    int*   cursor = (int*)  (ws + OFF_CURSOR);
    float* aggx   = (float*)(ws + OFF_AGGX);
    float* dis    = (float*)(ws + OFF_DIS);
    int*   rowptr = (int*)  (ws + OFF_ROWPTR);
    int2*  csr    = (int2*) (ws + OFF_CSR);
    float* h1     = (float*)(ws + OFF_H1);
    float* agg2   = (float*)(ws + OFF_AGG2);
    float* h2     = (float*)(ws + OFF_H2);
    float* z      = (float*)(ws + OFF_Z);
    float* tmp    = (float*)(ws + OFF_TMP);
    float* parts  = (float*)(ws + OFF_PART);

    // single contiguous zero: degi | cursor | aggx
    hipMemsetAsync(ws, 0, 0x60000, stream);

    deg_kernel <<<E_EDGES / 256, 256, 0, stream>>>(dst, degi);
    scan_kernel<<<1, 256, 0, stream>>>(degi, rowptr, dis);
    scatter_agg1_kernel<<<E_EDGES / 256, 256, 0, stream>>>(src, dst, x, dis, rowptr,
                                                           cursor, csr, aggx);
    h1_kernel  <<<(N_TOT * HID) / 256, 256, 0, stream>>>(aggx, x, dis, W1, b1, h1);
    agg2_gather_kernel<<<N_TOT / 4, 256, 0, stream>>>(rowptr, csr, h1, dis, agg2);
    h2_kernel  <<<N_TOT / 4, 256, 0, stream>>>(agg2, h1, dis, W2, b2, h2);
    fc1_kernel <<<NCHUNK, 512, 0, stream>>>(h2, Wf1, parts);
    fc1_reduce1_kernel<<<dim3(64, 8), 256, 0, stream>>>(parts, tmp);
    fc1_reduce2_kernel<<<64, 256, 0, stream>>>(tmp, bf1, z);
    fc2_kernel <<<B_GR, 64, 0, stream>>>(z, Wf2, bf2, out);
}